// Round 1
// baseline (174.335 us; speedup 1.0000x reference)
//
#include <hip/hip_runtime.h>

// Problem constants
static constexpr int BL = 128;          // B*L = 4*32
// ws layout (float offsets)
static constexpr int OFF_COS  = 0;        // cos(2*pi*h*s/32), symmetric [32][32]
static constexpr int OFF_SIN  = 1024;     // sin(2*pi*h*s/32)
static constexpr int OFF_ARE  = 2048;     // A = Wp1*Wb, [96][64]
static constexpr int OFF_AIM  = 8192;
static constexpr int OFF_WRE  = 14336;    // Wcp = Wc*Wp2, [64][96]
static constexpr int OFF_WIM  = 20480;
static constexpr int OFF_LRE  = 26624;    // lambda, [96][32]
static constexpr int OFF_LIM  = 29696;
static constexpr int OFF_GAM  = 32768;    // gamma, [96][32]
static constexpr int OFF_BH0R = 35840;    // 1024*Wp1*bb, [96]
static constexpr int OFF_BH0I = 35936;
static constexpr int OFF_BRR  = 36032;    // Re(Wc*bp2)+bc_r, [64]
static constexpr int OFF_QF   = 36096;    // qF [128][64][32] cplx interleaved
static constexpr int OFF_Y    = 560384;   // Y/S [128][96][32] cplx
static constexpr int OFF_V    = 1346816;  // V [128][64][32] cplx
static constexpr int OFF_R    = 1871104;  // R [128][64][32] real
static constexpr int OFF_ST   = 2133248;  // stats [128][2] (mu, istd)

__global__ __launch_bounds__(256) void k0_precompute(
    const float* __restrict__ params_log,
    const float* __restrict__ Wb_r, const float* __restrict__ Wb_i,
    const float* __restrict__ bb_r, const float* __restrict__ bb_i,
    const float* __restrict__ Wp1_r, const float* __restrict__ Wp1_i,
    const float* __restrict__ Wp2_r, const float* __restrict__ Wp2_i,
    const float* __restrict__ Wc_r, const float* __restrict__ Wc_i,
    const float* __restrict__ bp2_r, const float* __restrict__ bp2_i,
    const float* __restrict__ bc_r, float* __restrict__ ws) {
  int tid = blockIdx.x * 256 + threadIdx.x;
  if (tid < 1024) {
    int h = tid >> 5, s = tid & 31;
    int m = (h * s) & 31;
    float ang = (float)m * 0.19634954084936207f;  // 2*pi/32
    ws[OFF_COS + tid] = cosf(ang);
    ws[OFF_SIN + tid] = sinf(ang);
  } else if (tid < 4096) {
    int i = tid - 1024;  // c*32+h, c<96
    float nu = expf(params_log[i]);
    float th = expf(params_log[3072 + i]);
    float g  = expf(params_log[6144 + i]);
    float rr = expf(-nu);
    ws[OFF_LRE + i] = rr * cosf(th);
    ws[OFF_LIM + i] = rr * sinf(th);
    ws[OFF_GAM + i] = g;
  } else if (tid < 10240) {
    int i = tid - 4096;  // A[c][e]
    int c = i >> 6, e = i & 63;
    float are = 0.f, aim = 0.f;
    for (int k = 0; k < 96; ++k) {
      float pr = Wp1_r[c * 96 + k], pi = Wp1_i[c * 96 + k];
      float wr = Wb_r[k * 64 + e], wi = Wb_i[k * 64 + e];
      are += pr * wr - pi * wi;
      aim += pr * wi + pi * wr;
    }
    ws[OFF_ARE + i] = are;
    ws[OFF_AIM + i] = aim;
  } else if (tid < 16384) {
    int i = tid - 10240;  // Wcp[e][c]
    int e = i / 96, c = i - e * 96;
    float are = 0.f, aim = 0.f;
    for (int k = 0; k < 96; ++k) {
      float wr = Wc_r[e * 96 + k], wi = Wc_i[e * 96 + k];
      float pr = Wp2_r[k * 96 + c], pi = Wp2_i[k * 96 + c];
      are += wr * pr - wi * pi;
      aim += wr * pi + wi * pr;
    }
    ws[OFF_WRE + i] = are;
    ws[OFF_WIM + i] = aim;
  } else if (tid < 16480) {
    int c = tid - 16384;  // 1024 * (Wp1 . bb)[c]
    float re = 0.f, im = 0.f;
    for (int k = 0; k < 96; ++k) {
      float pr = Wp1_r[c * 96 + k], pi = Wp1_i[c * 96 + k];
      float br = bb_r[k], bi = bb_i[k];
      re += pr * br - pi * bi;
      im += pr * bi + pi * br;
    }
    ws[OFF_BH0R + c] = 1024.f * re;
    ws[OFF_BH0I + c] = 1024.f * im;
  } else if (tid < 16544) {
    int e = tid - 16480;  // Re(Wc . bp2)[e] + bc_r[e]
    float re = 0.f;
    for (int k = 0; k < 96; ++k)
      re += Wc_r[e * 96 + k] * bp2_r[k] - Wc_i[e * 96 + k] * bp2_i[k];
    ws[OFF_BRR + e] = re + bc_r[e];
  }
}

// Anti-diagonal sums + 32-pt DFT per (b,l,e) plane. One wave per plane.
__global__ __launch_bounds__(256) void k1_qdft(const float* __restrict__ x,
                                               float* __restrict__ ws) {
  __shared__ float pl[4][1024];
  __shared__ float qsh[4][32];
  int wave = threadIdx.x >> 6, lane = threadIdx.x & 63;
  int plane = blockIdx.x * 4 + wave;  // < 8192
  const float* xp = x + (size_t)plane * 1024;
#pragma unroll
  for (int j = 0; j < 16; ++j) pl[wave][j * 64 + lane] = xp[j * 64 + lane];
  __syncthreads();
  int s = lane & 31, half = lane >> 5;
  float acc = 0.f;
#pragma unroll
  for (int u0 = 0; u0 < 16; ++u0) {
    int u = half * 16 + u0;
    acc += pl[wave][u * 32 + ((s - u) & 31)];
  }
  acc += __shfl_xor(acc, 32);
  if (lane < 32) qsh[wave][lane] = acc;
  __syncthreads();
  int h = lane & 31;
  const float* Ft = ws + (lane < 32 ? OFF_COS : OFF_SIN);
  float sum = 0.f;
#pragma unroll
  for (int s2 = 0; s2 < 32; ++s2) sum += qsh[wave][s2] * Ft[s2 * 32 + h];
  if (lane >= 32) sum = -sum;  // imag part of e^{-i...}
  ws[OFF_QF + plane * 64 + h * 2 + (lane < 32 ? 0 : 1)] = sum;
}

// Y[bl,c,h] = gamma * (sum_e A[c,e]*qF[bl,e,h] + bh0*d(h==0) + bp1)
__global__ __launch_bounds__(256) void k2_mix1(float* __restrict__ ws,
                                               const float* __restrict__ bp1_r,
                                               const float* __restrict__ bp1_i) {
  __shared__ float qre[64][32], qim[64][32];
  int bl = blockIdx.x / 12, chunk = blockIdx.x % 12;
  const float2* qF = (const float2*)(ws + OFF_QF) + bl * 2048;
  for (int i = threadIdx.x; i < 2048; i += 256) {
    float2 v = qF[i];
    qre[i >> 5][i & 31] = v.x;
    qim[i >> 5][i & 31] = v.y;
  }
  __syncthreads();
  int c = chunk * 8 + (threadIdx.x >> 5), h = threadIdx.x & 31;
  const float* Ar = ws + OFF_ARE + c * 64;
  const float* Ai = ws + OFF_AIM + c * 64;
  float re = 0.f, im = 0.f;
#pragma unroll 8
  for (int e = 0; e < 64; ++e) {
    float ar = Ar[e], ai = Ai[e], qr = qre[e][h], qi = qim[e][h];
    re += ar * qr - ai * qi;
    im += ar * qi + ai * qr;
  }
  if (h == 0) { re += ws[OFF_BH0R + c]; im += ws[OFF_BH0I + c]; }
  re += bp1_r[c];
  im += bp1_i[c];
  float g = ws[OFF_GAM + c * 32 + h];
  ((float2*)(ws + OFF_Y))[(bl * 96 + c) * 32 + h] = make_float2(g * re, g * im);
}

// Sequential decay scan over L=32 per (b,c,h), in place on Y.
__global__ __launch_bounds__(256) void k3_scan(float* __restrict__ ws,
                                               const float* __restrict__ mask) {
  int tid = blockIdx.x * 256 + threadIdx.x;  // < 12288
  int b = tid / 3072, r = tid - b * 3072;    // r = c*32+h
  float lr = ws[OFF_LRE + r], li = ws[OFF_LIM + r];
  float2* Y = (float2*)(ws + OFF_Y) + (size_t)b * 32 * 3072 + r;
  float2 v = Y[0];
  float sr = v.x, si = v.y;
  for (int l = 1; l < 32; ++l) {
    float m = mask[b * 32 + l - 1];
    float cr = m * (lr * sr - li * si);
    float ci = m * (lr * si + li * sr);
    v = Y[l * 3072];
    sr = v.x + cr;
    si = v.y + ci;
    Y[l * 3072] = make_float2(sr, si);
  }
}

// V[bl,e,h] = sum_c Wcp[e,c] * S[bl,c,h]
__global__ __launch_bounds__(256) void k4_mix2(float* __restrict__ ws) {
  __shared__ float sre[96][32], sim_[96][32];
  int bl = blockIdx.x >> 3, chunk = blockIdx.x & 7;
  const float2* S = (const float2*)(ws + OFF_Y) + bl * 3072;
  for (int i = threadIdx.x; i < 3072; i += 256) {
    float2 v = S[i];
    sre[i >> 5][i & 31] = v.x;
    sim_[i >> 5][i & 31] = v.y;
  }
  __syncthreads();
  int e = chunk * 8 + (threadIdx.x >> 5), h = threadIdx.x & 31;
  const float* Wr = ws + OFF_WRE + e * 96;
  const float* Wi = ws + OFF_WIM + e * 96;
  float re = 0.f, im = 0.f;
#pragma unroll 8
  for (int c = 0; c < 96; ++c) {
    float wr = Wr[c], wi = Wi[c], a = sre[c][h], b2 = sim_[c][h];
    re += wr * a - wi * b2;
    im += wr * b2 + wi * a;
  }
  ((float2*)(ws + OFF_V))[(bl * 64 + e) * 32 + h] = make_float2(re, im);
}

// R[bl,e,s] = Re(inv-DFT of V)/1024 + bR[e]; LN stats per bl.
__global__ __launch_bounds__(256) void k5a_post(float* __restrict__ ws) {
  __shared__ float vre[64][32], vim[64][32];
  __shared__ float red[8];
  int bl = blockIdx.x;
  const float2* V = (const float2*)(ws + OFF_V) + bl * 2048;
  for (int i = threadIdx.x; i < 2048; i += 256) {
    float2 v = V[i];
    vre[i >> 5][i & 31] = v.x;
    vim[i >> 5][i & 31] = v.y;
  }
  __syncthreads();
  float sum = 0.f, sumsq = 0.f;
  float* R = ws + OFF_R + bl * 2048;
  for (int i = threadIdx.x; i < 2048; i += 256) {
    int e = i >> 5, s = i & 31;
    float acc = 0.f;
#pragma unroll
    for (int h = 0; h < 32; ++h)
      acc += vre[e][h] * ws[OFF_COS + h * 32 + s] - vim[e][h] * ws[OFF_SIN + h * 32 + s];
    float r = acc * (1.0f / 1024.0f) + ws[OFF_BRR + e];
    R[i] = r;
    sum += r;
    sumsq += r * r;
  }
#pragma unroll
  for (int off = 32; off > 0; off >>= 1) {
    sum += __shfl_down(sum, off);
    sumsq += __shfl_down(sumsq, off);
  }
  int wave = threadIdx.x >> 6, lane = threadIdx.x & 63;
  if (lane == 0) { red[wave] = sum; red[4 + wave] = sumsq; }
  __syncthreads();
  if (threadIdx.x == 0) {
    float s0 = red[0] + red[1] + red[2] + red[3];
    float q0 = red[4] + red[5] + red[6] + red[7];
    float mu = s0 * (1.0f / 2048.0f);
    float var = q0 * (1.0f / 2048.0f) - mu * mu;
    ws[OFF_ST + bl * 2] = mu;
    ws[OFF_ST + bl * 2 + 1] = rsqrtf(var + 1e-5f);
  }
}

// out = (R[bl,e,(u+v)&31]-mu)*istd*ln_w + ln_b + x
__global__ __launch_bounds__(256) void k5b_final(const float* __restrict__ x,
                                                 const float* __restrict__ lnw,
                                                 const float* __restrict__ lnb,
                                                 const float* __restrict__ ws,
                                                 float* __restrict__ out) {
  int gid = blockIdx.x * 256 + threadIdx.x;  // < 2097152 float4s
  int flat = gid * 4;
  int bl = flat >> 16;
  int rem = flat & 65535;
  int e = rem >> 10;
  int pos = rem & 1023;
  int u = pos >> 5, v = pos & 31;
  float mu = ws[OFF_ST + bl * 2], istd = ws[OFF_ST + bl * 2 + 1];
  const float* Rrow = ws + OFF_R + bl * 2048 + e * 32;
  const float4 xin = ((const float4*)x)[gid];
  const float4 lw = ((const float4*)lnw)[rem >> 2];
  const float4 lb = ((const float4*)lnb)[rem >> 2];
  float4 o;
  o.x = (Rrow[(u + v) & 31] - mu) * istd * lw.x + lb.x + xin.x;
  o.y = (Rrow[(u + v + 1) & 31] - mu) * istd * lw.y + lb.y + xin.y;
  o.z = (Rrow[(u + v + 2) & 31] - mu) * istd * lw.z + lb.z + xin.z;
  o.w = (Rrow[(u + v + 3) & 31] - mu) * istd * lw.w + lb.w + xin.w;
  ((float4*)out)[gid] = o;
}

extern "C" void kernel_launch(void* const* d_in, const int* in_sizes, int n_in,
                              void* d_out, int out_size, void* d_ws, size_t ws_size,
                              hipStream_t stream) {
  const float* x          = (const float*)d_in[0];
  const float* mask       = (const float*)d_in[1];
  const float* params_log = (const float*)d_in[2];
  const float* Wb_r  = (const float*)d_in[3];
  const float* Wb_i  = (const float*)d_in[4];
  const float* bb_r  = (const float*)d_in[5];
  const float* bb_i  = (const float*)d_in[6];
  const float* Wp1_r = (const float*)d_in[7];
  const float* Wp1_i = (const float*)d_in[8];
  const float* bp1_r = (const float*)d_in[9];
  const float* bp1_i = (const float*)d_in[10];
  const float* Wp2_r = (const float*)d_in[11];
  const float* Wp2_i = (const float*)d_in[12];
  const float* bp2_r = (const float*)d_in[13];
  const float* bp2_i = (const float*)d_in[14];
  const float* Wc_r  = (const float*)d_in[15];
  const float* Wc_i  = (const float*)d_in[16];
  const float* bc_r  = (const float*)d_in[17];
  // d_in[18] = bc_i: dropped by .real
  const float* ln_w  = (const float*)d_in[19];
  const float* ln_b  = (const float*)d_in[20];
  float* ws  = (float*)d_ws;
  float* out = (float*)d_out;

  k0_precompute<<<65, 256, 0, stream>>>(params_log, Wb_r, Wb_i, bb_r, bb_i,
                                        Wp1_r, Wp1_i, Wp2_r, Wp2_i, Wc_r, Wc_i,
                                        bp2_r, bp2_i, bc_r, ws);
  k1_qdft<<<2048, 256, 0, stream>>>(x, ws);
  k2_mix1<<<1536, 256, 0, stream>>>(ws, bp1_r, bp1_i);
  k3_scan<<<48, 256, 0, stream>>>(ws, mask);
  k4_mix2<<<1024, 256, 0, stream>>>(ws);
  k5a_post<<<128, 256, 0, stream>>>(ws);
  k5b_final<<<8192, 256, 0, stream>>>(x, ln_w, ln_b, ws, out);
}